// Round 1
// baseline (141.379 us; speedup 1.0000x reference)
//
#include <hip/hip_runtime.h>

// Problem constants (match reference)
constexpr int B        = 65536;
constexpr int N_SPARSE = 20;
constexpr int N_VARLEN = 3;
constexpr int SEQ_LEN  = 50;
constexpr int VOCAB    = 100000;
constexpr int N_DENSE  = 13;
constexpr int VAR_TOT  = N_VARLEN * SEQ_LEN;  // 150

// 4 threads cooperate on one row. lane layout: quad = 4 consecutive lanes,
// so id reads within a quad are 4 consecutive ints -> 16B coalesced segments.
__global__ __launch_bounds__(256) void logit_kernel(
    const int*   __restrict__ sparse_ids,    // [B, 20]
    const int*   __restrict__ varlen_ids,    // [B, 3, 50]
    const float* __restrict__ dense_x,       // [B, 13]
    const float* __restrict__ sparse_tables, // [20, VOCAB]
    const float* __restrict__ varlen_tables, // [3, VOCAB]
    const float* __restrict__ dense_w,       // [13]
    float*       __restrict__ out)           // [B]
{
    const int tid = blockIdx.x * blockDim.x + threadIdx.x;
    const int row = tid >> 2;
    const int t   = tid & 3;
    if (row >= B) return;

    float acc0 = 0.f, acc1 = 0.f;

    // ---- sparse: thread t handles features t, t+4, ..., t+16 (5 each) ----
    const int* srow = sparse_ids + (long)row * N_SPARSE;
    int sid[5];
    #pragma unroll
    for (int i = 0; i < 5; ++i) sid[i] = srow[t + 4 * i];   // issue all id loads first
    #pragma unroll
    for (int i = 0; i < 5; ++i) {
        const int f = t + 4 * i;
        acc0 += sparse_tables[f * VOCAB + sid[i]];
    }

    // ---- varlen: thread t handles positions t, t+4, ... < 150 ----
    // Batch id loads then gathers for ILP (independent loads in flight).
    const int* vrow = varlen_ids + (long)row * VAR_TOT;
    {
        // 38 iterations for t in {0,1}, 37 for t in {2,3}; process in chunks of 8
        int p = t;
        while (p + 28 < VAR_TOT) {          // full chunk of 8 positions
            int id[8];
            #pragma unroll
            for (int i = 0; i < 8; ++i) id[i] = vrow[p + 4 * i];
            #pragma unroll
            for (int i = 0; i < 8; ++i) {
                const int pp = p + 4 * i;
                const int v  = (pp >= 100) ? 2 : (pp >= 50 ? 1 : 0);
                const float val = varlen_tables[v * VOCAB + id[i]];
                if (i & 1) acc1 += (id[i] != 0) ? val : 0.f;
                else       acc0 += (id[i] != 0) ? val : 0.f;
            }
            p += 32;
        }
        for (; p < VAR_TOT; p += 4) {       // remainder (5 or 6 iters)
            const int id = vrow[p];
            const int v  = (p >= 100) ? 2 : (p >= 50 ? 1 : 0);
            const float val = varlen_tables[v * VOCAB + id];
            acc0 += (id != 0) ? val : 0.f;
        }
    }

    // ---- dense: thread t handles dims t, t+4, ... < 13 ----
    const float* drow = dense_x + (long)row * N_DENSE;
    #pragma unroll
    for (int d = t; d < N_DENSE; d += 4)
        acc1 += drow[d] * dense_w[d];

    // ---- quad reduction ----
    float acc = acc0 + acc1;
    acc += __shfl_xor(acc, 1);
    acc += __shfl_xor(acc, 2);
    if (t == 0) out[row] = acc;
}

extern "C" void kernel_launch(void* const* d_in, const int* in_sizes, int n_in,
                              void* d_out, int out_size, void* d_ws, size_t ws_size,
                              hipStream_t stream) {
    const int*   sparse_ids    = (const int*)d_in[0];
    const int*   varlen_ids    = (const int*)d_in[1];
    const float* dense_x       = (const float*)d_in[2];
    const float* sparse_tables = (const float*)d_in[3];
    const float* varlen_tables = (const float*)d_in[4];
    const float* dense_w       = (const float*)d_in[5];
    float*       out           = (float*)d_out;

    const int threads = 256;
    const int total   = B * 4;                 // 4 threads per row
    const int blocks  = (total + threads - 1) / threads;   // 1024
    logit_kernel<<<blocks, threads, 0, stream>>>(
        sparse_ids, varlen_ids, dense_x, sparse_tables, varlen_tables, dense_w, out);
}

// Round 2
// 136.903 us; speedup vs baseline: 1.0327x; 1.0327x over previous
//
#include <hip/hip_runtime.h>

// Problem constants (match reference)
constexpr int B        = 65536;
constexpr int N_SPARSE = 20;
constexpr int N_VARLEN = 3;
constexpr int SEQ_LEN  = 50;
constexpr int VOCAB    = 100000;
constexpr int N_DENSE  = 13;
constexpr int VAR_TOT  = N_VARLEN * SEQ_LEN;  // 150

// 16 lanes cooperate on a PAIR of rows (2g, 2g+1).
// Pair-based layout makes every vector load naturally aligned:
//   varlen pair: 300 ints = 75 int4 chunks, byte offset 1200*g (16B aligned)
//   sparse pair:  40 ints = 10 int4 chunks, byte offset  160*g (16B aligned)
//   dense  pair:  26 f32  = 13 float2,      byte offset  104*g ( 8B aligned)
//   out    pair:  float2 store at 8*g.
__global__ __launch_bounds__(256) void logit_kernel(
    const int*   __restrict__ sparse_ids,    // [B, 20]
    const int*   __restrict__ varlen_ids,    // [B, 3, 50]
    const float* __restrict__ dense_x,       // [B, 13]
    const float* __restrict__ sparse_tables, // [20, VOCAB]
    const float* __restrict__ varlen_tables, // [3, VOCAB]
    const float* __restrict__ dense_w,       // [13]
    float*       __restrict__ out)           // [B]
{
    const int tid = blockIdx.x * blockDim.x + threadIdx.x;
    const int g   = tid >> 4;     // row-pair index, 0 .. B/2-1
    const int t   = tid & 15;     // lane within pair-group

    const int4*   vptr = (const int4*)(varlen_ids) + (long)g * 75;
    const int4*   sptr = (const int4*)(sparse_ids) + (long)g * 10;
    const float2* dptr = (const float2*)(dense_x)  + (long)g * 13;

    // ---- issue ALL id / dense loads first (independent, stay in flight) ----
    int4 vid[5];
    #pragma unroll
    for (int k = 0; k < 4; ++k) vid[k] = vptr[t + 16 * k];   // chunks 0..63, all lanes
    const bool v5 = (t + 64) < 75;                           // chunks 64..74: lanes 0..10
    if (v5) vid[4] = vptr[t + 64];

    int4 sid;
    const bool hs = (t < 10);
    if (hs) sid = sptr[t];

    float2 dx;
    const bool hd = (t < 13);
    if (hd) dx = dptr[t];

    float acc0 = 0.f, acc1 = 0.f;   // row 2g, row 2g+1

    // ---- varlen gathers: chunk c covers pair-positions s = 4c .. 4c+3 (0..299) ----
    #pragma unroll
    for (int k = 0; k < 5; ++k) {
        if (k == 4 && !v5) continue;
        const int s0 = 4 * (t + 16 * k);
        const int ids[4] = { vid[k].x, vid[k].y, vid[k].z, vid[k].w };
        #pragma unroll
        for (int j = 0; j < 4; ++j) {
            const int s  = s0 + j;                       // 0..299
            const bool r1 = (s >= VAR_TOT);
            const int p  = r1 ? (s - VAR_TOT) : s;       // position in its row
            const int v  = (p >= 100) ? 2 : (p >= 50 ? 1 : 0);
            const float val = varlen_tables[v * VOCAB + ids[j]];
            const float m   = (ids[j] != 0) ? val : 0.f;
            acc0 += r1 ? 0.f : m;
            acc1 += r1 ? m   : 0.f;
        }
    }

    // ---- sparse gathers: chunk t covers s = 4t .. 4t+3 (0..39) ----
    if (hs) {
        const int s0 = 4 * t;
        const int ids[4] = { sid.x, sid.y, sid.z, sid.w };
        #pragma unroll
        for (int j = 0; j < 4; ++j) {
            const int s  = s0 + j;                       // 0..39
            const bool r1 = (s >= N_SPARSE);
            const int f  = r1 ? (s - N_SPARSE) : s;
            const float val = sparse_tables[f * VOCAB + ids[j]];
            acc0 += r1 ? 0.f : val;
            acc1 += r1 ? val : 0.f;
        }
    }

    // ---- dense: float2 t covers s = 2t, 2t+1 (0..25) ----
    if (hd) {
        const int s0 = 2 * t;
        {
            const int s = s0;
            const bool r1 = (s >= N_DENSE);
            const int d = r1 ? (s - N_DENSE) : s;
            const float prod = dx.x * dense_w[d];
            acc0 += r1 ? 0.f : prod;
            acc1 += r1 ? prod : 0.f;
        }
        {
            const int s = s0 + 1;
            const bool r1 = (s >= N_DENSE);
            const int d = r1 ? (s - N_DENSE) : s;
            const float prod = dx.y * dense_w[d];
            acc0 += r1 ? 0.f : prod;
            acc1 += r1 ? prod : 0.f;
        }
    }

    // ---- reduce across the 16-lane group ----
    #pragma unroll
    for (int o = 1; o < 16; o <<= 1) {
        acc0 += __shfl_xor(acc0, o);
        acc1 += __shfl_xor(acc1, o);
    }
    if (t == 0) ((float2*)out)[g] = make_float2(acc0, acc1);
}

extern "C" void kernel_launch(void* const* d_in, const int* in_sizes, int n_in,
                              void* d_out, int out_size, void* d_ws, size_t ws_size,
                              hipStream_t stream) {
    const int*   sparse_ids    = (const int*)d_in[0];
    const int*   varlen_ids    = (const int*)d_in[1];
    const float* dense_x       = (const float*)d_in[2];
    const float* sparse_tables = (const float*)d_in[3];
    const float* varlen_tables = (const float*)d_in[4];
    const float* dense_w       = (const float*)d_in[5];
    float*       out           = (float*)d_out;

    const int threads = 256;
    const int total   = (B / 2) * 16;          // 16 lanes per row-pair
    const int blocks  = total / threads;       // 2048
    logit_kernel<<<blocks, threads, 0, stream>>>(
        sparse_ids, varlen_ids, dense_x, sparse_tables, varlen_tables, dense_w, out);
}

// Round 3
// 136.777 us; speedup vs baseline: 1.0336x; 1.0009x over previous
//
#include <hip/hip_runtime.h>

// Problem constants (match reference)
constexpr int B        = 65536;
constexpr int N_SPARSE = 20;
constexpr int N_VARLEN = 3;
constexpr int SEQ_LEN  = 50;
constexpr int VOCAB    = 100000;
constexpr int N_DENSE  = 13;
constexpr int VAR_TOT  = N_VARLEN * SEQ_LEN;  // 150

constexpr int NB_VAR    = (B / 2) * 16 / 256; // 2048 varlen blocks (16 lanes/row-pair)
constexpr int NB_SPARSE = B / 256;            // 256 sparse blocks (1 row/thread)

// ---------------- Kernel 1: dense dot, initializes out ----------------
__global__ __launch_bounds__(256) void dense_kernel(
    const float* __restrict__ dense_x,   // [B, 13]
    const float* __restrict__ dense_w,   // [13]
    float*       __restrict__ out)       // [B]
{
    const int row = blockIdx.x * blockDim.x + threadIdx.x;
    if (row >= B) return;
    const float* drow = dense_x + (long)row * N_DENSE;
    float acc = 0.f;
    #pragma unroll
    for (int d = 0; d < N_DENSE; ++d) acc += drow[d] * dense_w[d];
    out[row] = acc;
}

// ---------------- Kernel 2: phased gathers ----------------
// Blocks [0, NB_VAR): varlen gathers (1.2 MB tables -> L2-resident per XCD).
//   16 lanes per row-pair; 75 aligned int4 id loads per pair.
// Blocks [NB_VAR, NB_VAR+NB_SPARSE): sparse gathers (8 MB tables, L3-bound),
//   dispatched last so they fill the varlen drain tail. 1 row per thread,
//   5 aligned int4 id loads (row stride 80 B = 5x16 B).
__global__ __launch_bounds__(256) void gather_kernel(
    const int*   __restrict__ sparse_ids,    // [B, 20]
    const int*   __restrict__ varlen_ids,    // [B, 3, 50]
    const float* __restrict__ sparse_tables, // [20, VOCAB]
    const float* __restrict__ varlen_tables, // [3, VOCAB]
    float*       __restrict__ out)           // [B]
{
    if (blockIdx.x < NB_VAR) {
        // ================= varlen phase =================
        const int tid = blockIdx.x * blockDim.x + threadIdx.x;
        const int g   = tid >> 4;     // row-pair index
        const int t   = tid & 15;     // lane within pair-group

        const int4* vptr = (const int4*)(varlen_ids) + (long)g * 75;

        // issue all id loads first
        int4 vid[5];
        #pragma unroll
        for (int k = 0; k < 4; ++k) vid[k] = vptr[t + 16 * k];   // chunks 0..63
        const bool v5 = (t + 64) < 75;                           // chunks 64..74
        if (v5) vid[4] = vptr[t + 64];

        float acc0 = 0.f, acc1 = 0.f;   // rows 2g, 2g+1

        #pragma unroll
        for (int k = 0; k < 5; ++k) {
            if (k == 4 && !v5) continue;
            const int s0 = 4 * (t + 16 * k);
            const int ids[4] = { vid[k].x, vid[k].y, vid[k].z, vid[k].w };
            #pragma unroll
            for (int j = 0; j < 4; ++j) {
                const int s  = s0 + j;                      // 0..299 pair-position
                const bool r1 = (s >= VAR_TOT);
                const int p  = r1 ? (s - VAR_TOT) : s;      // position within row
                const int v  = (p >= 100) ? 2 : (p >= 50 ? 1 : 0);
                const float val = varlen_tables[v * VOCAB + ids[j]];
                const float m   = (ids[j] != 0) ? val : 0.f;
                acc0 += r1 ? 0.f : m;
                acc1 += r1 ? m   : 0.f;
            }
        }

        #pragma unroll
        for (int o = 1; o < 16; o <<= 1) {
            acc0 += __shfl_xor(acc0, o);
            acc1 += __shfl_xor(acc1, o);
        }
        if (t == 0) {
            atomicAdd(out + 2 * g,     acc0);
            atomicAdd(out + 2 * g + 1, acc1);
        }
    } else {
        // ================= sparse phase (tail) =================
        const int row = (blockIdx.x - NB_VAR) * blockDim.x + threadIdx.x;
        if (row >= B) return;

        const int4* sptr = (const int4*)(sparse_ids) + (long)row * 5;
        int4 sid[5];
        #pragma unroll
        for (int k = 0; k < 5; ++k) sid[k] = sptr[k];   // 20 ids, aligned

        float acc = 0.f;
        #pragma unroll
        for (int k = 0; k < 5; ++k) {
            const int ids[4] = { sid[k].x, sid[k].y, sid[k].z, sid[k].w };
            #pragma unroll
            for (int j = 0; j < 4; ++j) {
                const int f = 4 * k + j;
                acc += sparse_tables[f * VOCAB + ids[j]];
            }
        }
        atomicAdd(out + row, acc);
    }
}

extern "C" void kernel_launch(void* const* d_in, const int* in_sizes, int n_in,
                              void* d_out, int out_size, void* d_ws, size_t ws_size,
                              hipStream_t stream) {
    const int*   sparse_ids    = (const int*)d_in[0];
    const int*   varlen_ids    = (const int*)d_in[1];
    const float* dense_x       = (const float*)d_in[2];
    const float* sparse_tables = (const float*)d_in[3];
    const float* varlen_tables = (const float*)d_in[4];
    const float* dense_w       = (const float*)d_in[5];
    float*       out           = (float*)d_out;

    dense_kernel<<<B / 256, 256, 0, stream>>>(dense_x, dense_w, out);
    gather_kernel<<<NB_VAR + NB_SPARSE, 256, 0, stream>>>(
        sparse_ids, varlen_ids, sparse_tables, varlen_tables, out);
}